// Round 15
// baseline (26.967 us; speedup 1.0000x reference)
//
#include <hip/hip_runtime.h>

// MedianBlur 5x5, fp32 in/out, reflect padding.
// R15: residency-persistent blocks — 2048 blocks x 256 threads (8 blocks/CU,
// 32 waves/CU static) each looping over 3 tiles. Fixes the measured occupancy
// collapse (R12: 24.6%) caused by short-lived blocks draining faster than the
// dispatcher refills. No register pipelining (R10's failure) — plain
// stage -> barrier -> compute -> barrier per tile; inter-block TLP hides the
// staging latency. u16-packed forgetful-selection median.

typedef unsigned short u2 __attribute__((ext_vector_type(2)));
typedef unsigned short u4 __attribute__((ext_vector_type(4)));
typedef _Float16 h2f __attribute__((ext_vector_type(2)));
typedef float f2 __attribute__((ext_vector_type(2)));

constexpr int H = 512;
constexpr int W = 512;
constexpr int HW = H * W;
constexpr int PLANES = 8 * 3;          // 24 planes -> 12 plane-pairs
constexpr int BW = 32;                 // output cols per tile
constexpr int BHR = 16;                // output rows per tile
constexpr int TXH = BW / 2;            // 16 threads in x, 2 cols each
constexpr int LW = BW + 4;             // 36
constexpr int LH = BHR + 4;            // 20
constexpr int NT = 256;
constexpr int NHALO = LH * LW;         // 720
constexpr int NBX = W / BW;            // 16
constexpr int NBY = H / BHR;           // 32
constexpr int NTILE = NBX * NBY * (PLANES / 2);  // 6144
constexpr int TPB = 3;                 // tiles per block
constexpr int NBLK = NTILE / TPB;      // 2048 (divisible by 8)
constexpr int CHUNK = NTILE / 8;       // 768 tiles per XCD
constexpr size_t NPIX = (size_t)PLANES * HW;

__device__ __forceinline__ void ce(u2& a, u2& b) {
    u2 lo = __builtin_elementwise_min(a, b);   // v_pk_min_u16
    u2 hi = __builtin_elementwise_max(a, b);   // v_pk_max_u16
    a = lo;
    b = hi;
}

template<int M>
__device__ __forceinline__ void stage(u2* c) {
#pragma unroll
    for (int i = 0; i + 1 < M; i += 2) ce(c[i], c[i + 1]);
    if constexpr (M % 2 == 0) {
#pragma unroll
        for (int i = 2; i <= M - 2; i += 2) ce(c[0], c[i]);
#pragma unroll
        for (int i = 1; i <= M - 3; i += 2) ce(c[i], c[M - 1]);
    } else {
#pragma unroll
        for (int i = 2; i <= M - 3; i += 2) ce(c[0], c[i]);
        ce(c[0], c[M - 1]);
#pragma unroll
        for (int i = 1; i <= M - 2; i += 2) ce(c[i], c[M - 1]);
    }
}

// Exact rank-6-of-11 (7 discarded below / 7 above globally -> middle of 11).
__device__ __forceinline__ u2 median11(u2* d) {
    stage<11>(d);
    stage<9>(d + 1);
    stage<7>(d + 2);
    stage<5>(d + 3);
    u2 mn = __builtin_elementwise_min(d[4], d[5]);
    u2 mx = __builtin_elementwise_max(d[4], d[5]);
    return __builtin_elementwise_max(mn, __builtin_elementwise_min(mx, d[6]));
}

__device__ __forceinline__ int reflect_off(int by, int bx, int i) {
    int r = i / LW;
    int c = i - r * LW;
    int gy = by + r - 2;
    gy = (gy < 0) ? -gy : ((gy >= H) ? (2 * H - 2 - gy) : gy);
    int gx = bx + c - 2;
    gx = (gx < 0) ? -gx : ((gx >= W) ? (2 * W - 2 - gx) : gx);
    return gy * W + gx;
}

__global__ __launch_bounds__(256, 8)
void median5_kernel(const float* __restrict__ in, float* __restrict__ out) {
    __shared__ u2 tile[LH][LW];        // 20x36 plane-pair packed halo tile

    const int b = blockIdx.x;
    const int tid = threadIdx.x;       // 0..255
    const int tx = tid & (TXH - 1);    // 0..15 (cols 2tx, 2tx+1)
    const int ty = tid >> 4;           // 0..15 (output row)
    const bool has2 = tid < (NHALO - 2 * NT);   // 208 threads

    if (b == 0 && tid == 0) out[NPIX] = 5.0f;   // scalar second output

    // Block's 3 contiguous tiles within its XCD chunk (b&7 -> XCD).
    const int s0 = (b & 7) * CHUNK + (b >> 3) * TPB;

#pragma unroll 1
    for (int k = 0; k < TPB; ++k) {
        const int s = s0 + k;
        const int bx = (s & (NBX - 1)) * BW;
        const int by = ((s >> 4) & (NBY - 1)) * BHR;
        const int zp = (s >> 9) * 2;

        const float* __restrict__ pa = in + (size_t)zp * HW;
        const float* __restrict__ pb = pa + HW;

        // Stage halo (720 elems, 256 threads -> 2 + 208); loads issued
        // together so their L2/HBM latencies overlap.
        const int o0 = reflect_off(by, bx, tid);
        const int o1 = reflect_off(by, bx, tid + NT);
        const int o2 = reflect_off(by, bx, has2 ? (tid + 2 * NT) : tid);
        float a0 = pa[o0], fb0 = pb[o0];
        float a1 = pa[o1], fb1 = pb[o1];
        float a2 = pa[o2], fb2 = pb[o2];
        ((u2*)tile)[tid] = __builtin_bit_cast(u2, __builtin_amdgcn_cvt_pkrtz(a0, fb0));
        ((u2*)tile)[tid + NT] = __builtin_bit_cast(u2, __builtin_amdgcn_cvt_pkrtz(a1, fb1));
        if (has2) {
            ((u2*)tile)[tid + 2 * NT] = __builtin_bit_cast(u2, __builtin_amdgcn_cvt_pkrtz(a2, fb2));
        }
        __syncthreads();

        // Gather window: tile rows ty..ty+4, cols 2tx..2tx+5 (3 x 8B per row).
        u2 w[30];                      // row-major [5][6]
#pragma unroll
        for (int rr = 0; rr < 5; ++rr) {
            const u4* rowp = (const u4*)&tile[ty + rr][2 * tx];
            u4 q0 = rowp[0];
            u4 q1 = rowp[1];
            u4 q2 = rowp[2];
            w[rr * 6 + 0] = q0.xy;
            w[rr * 6 + 1] = q0.zw;
            w[rr * 6 + 2] = q1.xy;
            w[rr * 6 + 3] = q1.zw;
            w[rr * 6 + 4] = q2.xy;
            w[rr * 6 + 5] = q2.zw;
        }
        // All LDS reads done; release the buffer for the next iteration.
        __syncthreads();

        // Shared forgetful phase on the 20 elems common to both windows
        // (cols 1..4 of each row). At every discard: prior-discards + unseen
        // (remaining shared inserts + 5 exclusive) <= 11 < 12 -> safe.
        u2 c[14];
        c[0] = w[1];  c[1] = w[2];  c[2] = w[3];  c[3] = w[4];
        c[4] = w[7];  c[5] = w[8];  c[6] = w[9];  c[7] = w[10];
        c[8] = w[13]; c[9] = w[14]; c[10] = w[15]; c[11] = w[16];
        c[12] = w[19]; c[13] = w[20];
        stage<14>(c); c[0] = w[21];
        stage<13>(c); c[0] = w[22];
        stage<12>(c); c[0] = w[25];
        stage<11>(c); c[0] = w[26];
        stage<10>(c); c[0] = w[27];
        stage<9>(c);  c[0] = w[28];
        stage<8>(c);
        // Survivors c[1..6]; 7 shared discarded below, 7 above.

        u2 d[11];

        // Left output (col 2tx): exclusive col 0 -> w[0,6,12,18,24].
#pragma unroll
        for (int i = 0; i < 6; ++i) d[i] = c[1 + i];
        d[6] = w[0]; d[7] = w[6]; d[8] = w[12]; d[9] = w[18]; d[10] = w[24];
        u2 med_l = median11(d);

        // Right output (col 2tx+1): exclusive col 5 -> w[5,11,17,23,29].
#pragma unroll
        for (int i = 0; i < 6; ++i) d[i] = c[1 + i];
        d[6] = w[5]; d[7] = w[11]; d[8] = w[17]; d[9] = w[23]; d[10] = w[29];
        u2 med_r = median11(d);

        h2f hl = __builtin_bit_cast(h2f, med_l);
        h2f hr = __builtin_bit_cast(h2f, med_r);

        float* __restrict__ oa = out + (size_t)zp * HW;
        float* __restrict__ ob = oa + HW;
        const int o = (by + ty) * W + (bx + 2 * tx);   // even -> 8B aligned
        f2 va = { (float)hl.x, (float)hr.x };
        f2 vb = { (float)hl.y, (float)hr.y };
        *(f2*)&oa[o] = va;
        *(f2*)&ob[o] = vb;
    }
}

extern "C" void kernel_launch(void* const* d_in, const int* in_sizes, int n_in,
                              void* d_out, int out_size, void* d_ws, size_t ws_size,
                              hipStream_t stream) {
    const float* in = (const float*)d_in[0];
    float* out = (float*)d_out;

    median5_kernel<<<dim3(NBLK), dim3(NT), 0, stream>>>(in, out);
}

// Round 16
// 25.330 us; speedup vs baseline: 1.0646x; 1.0646x over previous
//
#include <hip/hip_runtime.h>

// MedianBlur 5x5, fp32 in/out, reflect padding.
// R16: barrier-free register-sliding-window. Each thread owns (plane-pair,
// col-pair, 8-row strip); the 5x6 window lives in registers, one new row is
// loaded per step (software-pipelined one step ahead, hidden under the CE
// network). No LDS, no __syncthreads -> no phase-lockstep stalls.
// u16-packed forgetful-selection median (fp16 bits of nonneg floats order as
// unsigned; v_pk_min_u16/v_pk_max_u16). Median is row-order invariant, so
// slot rotation needs no data movement.

typedef unsigned short u2 __attribute__((ext_vector_type(2)));
typedef _Float16 h2f __attribute__((ext_vector_type(2)));
typedef float f2 __attribute__((ext_vector_type(2)));

constexpr int H = 512;
constexpr int W = 512;
constexpr int HW = H * W;
constexpr int PLANES = 8 * 3;          // 24 planes -> 12 plane-pairs
constexpr int STRIP = 8;               // output rows per thread
constexpr int NSTRIP = H / STRIP;      // 64
constexpr int NPAIR = PLANES / 2;      // 12
constexpr int NT = 256;                // threads = W/2 col-pairs
constexpr int NBLK = NSTRIP * NPAIR;   // 768 (divisible by 8)
constexpr int CHUNK = NBLK / 8;        // 96 blocks per XCD
constexpr size_t NPIX = (size_t)PLANES * HW;

__device__ __forceinline__ u2 pk(float a, float b) {
    return __builtin_bit_cast(u2, __builtin_amdgcn_cvt_pkrtz(a, b));
}

__device__ __forceinline__ int refl(int v, int n) {
    return (v < 0) ? -v : ((v >= n) ? (2 * n - 2 - v) : v);
}

__device__ __forceinline__ void ce(u2& a, u2& b) {
    u2 lo = __builtin_elementwise_min(a, b);   // v_pk_min_u16
    u2 hi = __builtin_elementwise_max(a, b);   // v_pk_max_u16
    a = lo;
    b = hi;
}

template<int M>
__device__ __forceinline__ void stage(u2* c) {
#pragma unroll
    for (int i = 0; i + 1 < M; i += 2) ce(c[i], c[i + 1]);
    if constexpr (M % 2 == 0) {
#pragma unroll
        for (int i = 2; i <= M - 2; i += 2) ce(c[0], c[i]);
#pragma unroll
        for (int i = 1; i <= M - 3; i += 2) ce(c[i], c[M - 1]);
    } else {
#pragma unroll
        for (int i = 2; i <= M - 3; i += 2) ce(c[0], c[i]);
        ce(c[0], c[M - 1]);
#pragma unroll
        for (int i = 1; i <= M - 2; i += 2) ce(c[i], c[M - 1]);
    }
}

// Exact rank-6-of-11 (7 discarded below / 7 above globally -> middle of 11).
__device__ __forceinline__ u2 median11(u2* d) {
    stage<11>(d);
    stage<9>(d + 1);
    stage<7>(d + 2);
    stage<5>(d + 3);
    u2 mn = __builtin_elementwise_min(d[4], d[5]);
    u2 mx = __builtin_elementwise_max(d[4], d[5]);
    return __builtin_elementwise_max(mn, __builtin_elementwise_min(mx, d[6]));
}

__global__ __launch_bounds__(256)
void median5_kernel(const float* __restrict__ in, float* __restrict__ out) {
    // Bijective chunked XCD swizzle: 96 consecutive (pair,strip) units per
    // XCD -> adjacent strips (sharing halo rows) hit the same XCD's L2.
    const int b = blockIdx.x;
    const int s = (b & 7) * CHUNK + (b >> 3);
    const int strip = s & (NSTRIP - 1);
    const int pair = s >> 6;

    const int tx = threadIdx.x;            // 0..255 -> cols 2tx, 2tx+1
    const int y0 = strip * STRIP;
    const int gx0 = 2 * tx - 2;            // leftmost window col (even)
    const bool interior = (tx >= 1) && (tx <= NT - 2);

    const float* __restrict__ pa = in + (size_t)pair * 2 * HW;
    const float* __restrict__ pb = pa + HW;
    float* __restrict__ oa = out + (size_t)pair * 2 * HW;
    float* __restrict__ ob = oa + HW;

    if (b == 0 && tx == 0) out[NPIX] = 5.0f;   // scalar second output

    u2 w[5][6];                            // 5 row slots x 6 cols (packed pair)

    auto load_row = [&](int gy, f2* la, f2* lb) {
        const float* __restrict__ ra = pa + gy * W;
        const float* __restrict__ rb = pb + gy * W;
        if (interior) {
            la[0] = *(const f2*)&ra[gx0];
            la[1] = *(const f2*)&ra[gx0 + 2];
            la[2] = *(const f2*)&ra[gx0 + 4];
            lb[0] = *(const f2*)&rb[gx0];
            lb[1] = *(const f2*)&rb[gx0 + 2];
            lb[2] = *(const f2*)&rb[gx0 + 4];
        } else {
#pragma unroll
            for (int j = 0; j < 6; ++j) {
                const int cx = refl(gx0 + j, W);
                ((float*)la)[j] = ra[cx];
                ((float*)lb)[j] = rb[cx];
            }
        }
    };

    auto pack_slot = [&](int slot, const f2* la, const f2* lb) {
        w[slot][0] = pk(la[0].x, lb[0].x);
        w[slot][1] = pk(la[0].y, lb[0].y);
        w[slot][2] = pk(la[1].x, lb[1].x);
        w[slot][3] = pk(la[1].y, lb[1].y);
        w[slot][4] = pk(la[2].x, lb[2].x);
        w[slot][5] = pk(la[2].y, lb[2].y);
    };

    // Prologue: rows y0-2 .. y0+2 into slots 0..4 (independent iterations ->
    // compiler renames la/lb and overlaps the 30 loads).
#pragma unroll
    for (int r = 0; r < 5; ++r) {
        f2 la[3], lb[3];
        load_row(refl(y0 - 2 + r, H), la, lb);
        pack_slot(r, la, lb);
    }

    // Pipeline registers: next row in flight.
    f2 na[3], nb[3];
    load_row(refl(y0 + 3, H), na, nb);

#pragma unroll
    for (int t = 0; t < STRIP; ++t) {
        // ---- compute output row y0+t from the 5 slots (order-invariant) ----
        // Shared forgetful phase on the 20 elems common to both windows
        // (cols 1..4 of every slot). At every discard: prior-discards +
        // unseen (remaining shared + 5 exclusive) <= 11 < 12 -> safe.
        u2 c[14];
        c[0]  = w[0][1]; c[1]  = w[0][2]; c[2]  = w[0][3]; c[3]  = w[0][4];
        c[4]  = w[1][1]; c[5]  = w[1][2]; c[6]  = w[1][3]; c[7]  = w[1][4];
        c[8]  = w[2][1]; c[9]  = w[2][2]; c[10] = w[2][3]; c[11] = w[2][4];
        c[12] = w[3][1]; c[13] = w[3][2];
        stage<14>(c); c[0] = w[3][3];
        stage<13>(c); c[0] = w[3][4];
        stage<12>(c); c[0] = w[4][1];
        stage<11>(c); c[0] = w[4][2];
        stage<10>(c); c[0] = w[4][3];
        stage<9>(c);  c[0] = w[4][4];
        stage<8>(c);
        // Survivors c[1..6]; 7 shared discarded below, 7 above.

        u2 d[11];
#pragma unroll
        for (int i = 0; i < 6; ++i) d[i] = c[1 + i];
        d[6] = w[0][0]; d[7] = w[1][0]; d[8] = w[2][0]; d[9] = w[3][0]; d[10] = w[4][0];
        u2 med_l = median11(d);            // left output (col 2tx)

#pragma unroll
        for (int i = 0; i < 6; ++i) d[i] = c[1 + i];
        d[6] = w[0][5]; d[7] = w[1][5]; d[8] = w[2][5]; d[9] = w[3][5]; d[10] = w[4][5];
        u2 med_r = median11(d);            // right output (col 2tx+1)

        h2f hl = __builtin_bit_cast(h2f, med_l);
        h2f hr = __builtin_bit_cast(h2f, med_r);

        const int o = (y0 + t) * W + 2 * tx;   // even -> 8B aligned
        f2 va = { (float)hl.x, (float)hr.x };
        f2 vb = { (float)hl.y, (float)hr.y };
        *(f2*)&oa[o] = va;
        *(f2*)&ob[o] = vb;

        // ---- slide window: commit in-flight row, issue the next one ----
        if (t < STRIP - 1) {
            pack_slot(t % 5, na, nb);          // row y0+3+t replaces y0+t-2
            if (t < STRIP - 2) {
                load_row(refl(y0 + 4 + t, H), na, nb);   // lands during t+1's CE
            }
        }
    }
}

extern "C" void kernel_launch(void* const* d_in, const int* in_sizes, int n_in,
                              void* d_out, int out_size, void* d_ws, size_t ws_size,
                              hipStream_t stream) {
    const float* in = (const float*)d_in[0];
    float* out = (float*)d_out;

    median5_kernel<<<dim3(NBLK), dim3(NT), 0, stream>>>(in, out);
}